// Round 3
// baseline (14998.663 us; speedup 1.0000x reference)
//
#include <hip/hip_runtime.h>
#include <hip/hip_bf16.h>
#include <math.h>

// Problem constants (match reference)
#define V_ 32000
#define D_ 1024
#define E_ 8
#define H_ 4096
#define T_ 2048
#define NHOPS_ 4
#define K_ 2
#define EPS_ 1e-5f

// GEMM tiling
#define BM 64
#define BN 64
#define BK 16

__device__ __forceinline__ float gelu_f(float x) {
  // JAX default: approximate (tanh) gelu
  float x3 = x * x * x;
  return 0.5f * x * (1.0f + tanhf(0.7978845608028654f * (x + 0.044715f * x3)));
}

// ---------------- gather: h[t,:] = embed_W[ids[t],:] ----------------
__global__ void k_gather(const int* __restrict__ ids, const float* __restrict__ embed,
                         float* __restrict__ h) {
  int t = blockIdx.x;
  const float4* src = (const float4*)(embed + (size_t)ids[t] * D_);
  float4* dst = (float4*)(h + (size_t)t * D_);
  // D_/4 = 256 float4 per row, 256 threads
  dst[threadIdx.x] = src[threadIdx.x];
}

// ---------------- router: invr, top-2 expert ids + gates ----------------
__global__ void k_router(const float* __restrict__ h, const float* __restrict__ rln,
                         const float* __restrict__ rW, float* __restrict__ invr,
                         int* __restrict__ eidx, float* __restrict__ gate) {
  int t = blockIdx.x;
  int tid = threadIdx.x;
  const float* hp = h + (size_t)t * D_;
  float lacc[E_] = {0.f, 0.f, 0.f, 0.f, 0.f, 0.f, 0.f, 0.f};
  float ss = 0.f;
  for (int d = tid; d < D_; d += 256) {
    float x = hp[d];
    ss += x * x;
    float xw = x * rln[d];
    const float* wr = rW + (size_t)d * E_;
#pragma unroll
    for (int e = 0; e < E_; ++e) lacc[e] += xw * wr[e];
  }
  __shared__ float s_l[256][E_];
  __shared__ float s_ss[256];
  __shared__ float s_lg[E_];
  __shared__ float s_ir;
#pragma unroll
  for (int e = 0; e < E_; ++e) s_l[tid][e] = lacc[e];
  s_ss[tid] = ss;
  __syncthreads();
  if (tid < E_) {
    float a = 0.f;
    for (int i = 0; i < 256; ++i) a += s_l[i][tid];
    s_lg[tid] = a;
  } else if (tid == E_) {
    float tot = 0.f;
    for (int i = 0; i < 256; ++i) tot += s_ss[i];
    s_ir = rsqrtf(tot / (float)D_ + EPS_);
  }
  __syncthreads();
  if (tid == 0) {
    float ir = s_ir;
    invr[t] = ir;
    float lg[E_];
#pragma unroll
    for (int e = 0; e < E_; ++e) lg[e] = s_lg[e] * ir;
    // top-2 (ties -> lower index, matching lax.top_k)
    int i0 = 0;
#pragma unroll
    for (int e = 1; e < E_; ++e)
      if (lg[e] > lg[i0]) i0 = e;
    int i1 = (i0 == 0) ? 1 : 0;
#pragma unroll
    for (int e = 0; e < E_; ++e)
      if (e != i0 && lg[e] > lg[i1]) i1 = e;
    // softmax over ALL E logits, sampled at top-2
    float m = lg[0];
#pragma unroll
    for (int e = 1; e < E_; ++e) m = fmaxf(m, lg[e]);
    float den = 0.f;
#pragma unroll
    for (int e = 0; e < E_; ++e) den += expf(lg[e] - m);
    eidx[t * 2 + 0] = i0;
    eidx[t * 2 + 1] = i1;
    gate[t * 2 + 0] = expf(lg[i0] - m) / den;
    gate[t * 2 + 1] = expf(lg[i1] - m) / den;
  }
}

// ---------------- grouping ----------------
__global__ void k_zero_counts(int* counts, int* cursor) {
  if (threadIdx.x < E_) {
    counts[threadIdx.x] = 0;
    cursor[threadIdx.x] = 0;
  }
}
__global__ void k_count(const int* __restrict__ eidx, int* __restrict__ counts) {
  int i = blockIdx.x * 256 + threadIdx.x;
  if (i < T_ * K_) atomicAdd(&counts[eidx[i]], 1);
}
__global__ void k_scan(const int* __restrict__ counts, int* __restrict__ offsets) {
  if (threadIdx.x == 0) {
    int a = 0;
    for (int e = 0; e < E_; ++e) {
      offsets[e] = a;
      a += counts[e];
    }
  }
}
__global__ void k_fill(const int* __restrict__ eidx, const float* __restrict__ gate,
                       const int* __restrict__ offsets, int* __restrict__ cursor,
                       int* __restrict__ rowtok, float* __restrict__ rowgate) {
  int i = blockIdx.x * 256 + threadIdx.x;
  if (i >= T_ * K_) return;
  int e = eidx[i];
  int p = atomicAdd(&cursor[e], 1);
  int r = offsets[e] + p;
  rowtok[r] = i >> 1;  // token id
  rowgate[r] = gate[i];
}

// ---------------- expert GEMM1: u = gelu((h*invr*eln_e) @ W1_e) ----------------
__global__ void k_expert_gemm1(const float* __restrict__ h, const float* __restrict__ invr,
                               const float* __restrict__ eln, const float* __restrict__ W1,
                               const int* __restrict__ counts, const int* __restrict__ offsets,
                               const int* __restrict__ rowtok, float* __restrict__ u) {
  int e = blockIdx.z;
  int cnt = counts[e];
  int m0 = blockIdx.x * BM;
  if (m0 >= cnt) return;
  int n0 = blockIdx.y * BN;
  int base = offsets[e];
  __shared__ float As[BK][BM];
  __shared__ float Bs[BK][BN];
  int tid = threadIdx.x;
  int tx = tid % 16, ty = tid / 16;
  float acc[4][4] = {};
  // A load mapping: 64 rows x 4 threads each loading 4 k's
  int am = tid >> 2;
  int akq = (tid & 3) * 4;
  int arow = m0 + am;
  int tok = 0;
  float sc = 0.f;
  if (arow < cnt) {
    tok = rowtok[base + arow];
    sc = invr[tok];
  }
  const float* hA = h + (size_t)tok * D_;
  const float* elnE = eln + (size_t)e * D_;
  // B load mapping: 16 k x 16 threads each loading 4 n's
  int bk = tid >> 4;
  int bn = (tid & 15) * 4;
  const float* W1e = W1 + (size_t)e * D_ * H_;
  for (int k0 = 0; k0 < D_; k0 += BK) {
#pragma unroll
    for (int q = 0; q < 4; ++q) {
      int k = akq + q;
      float v = 0.f;
      if (arow < cnt) v = hA[k0 + k] * sc * elnE[k0 + k];
      As[k][am] = v;
    }
    const float* bp = W1e + (size_t)(k0 + bk) * H_ + n0 + bn;
#pragma unroll
    for (int q = 0; q < 4; ++q) Bs[bk][bn + q] = bp[q];
    __syncthreads();
#pragma unroll
    for (int kk = 0; kk < BK; ++kk) {
      float a[4], b[4];
#pragma unroll
      for (int i = 0; i < 4; ++i) a[i] = As[kk][ty * 4 + i];
#pragma unroll
      for (int j = 0; j < 4; ++j) b[j] = Bs[kk][tx * 4 + j];
#pragma unroll
      for (int i = 0; i < 4; ++i)
#pragma unroll
        for (int j = 0; j < 4; ++j) acc[i][j] += a[i] * b[j];
    }
    __syncthreads();
  }
#pragma unroll
  for (int i = 0; i < 4; ++i) {
    int r = m0 + ty * 4 + i;
    if (r < cnt) {
      float* up = u + (size_t)(base + r) * H_ + n0 + tx * 4;
#pragma unroll
      for (int j = 0; j < 4; ++j) up[j] = gelu_f(acc[i][j]);
    }
  }
}

// ---------------- expert GEMM2: h[tok] += gate * (u @ W2_e) ----------------
__global__ void k_expert_gemm2(const float* __restrict__ u, const float* __restrict__ W2,
                               const int* __restrict__ counts, const int* __restrict__ offsets,
                               const int* __restrict__ rowtok, const float* __restrict__ rowgate,
                               float* __restrict__ h) {
  int e = blockIdx.z;
  int cnt = counts[e];
  int m0 = blockIdx.x * BM;
  if (m0 >= cnt) return;
  int n0 = blockIdx.y * BN;
  int base = offsets[e];
  __shared__ float As[BK][BM];
  __shared__ float Bs[BK][BN];
  int tid = threadIdx.x;
  int tx = tid % 16, ty = tid / 16;
  float acc[4][4] = {};
  int am = tid >> 2;
  int akq = (tid & 3) * 4;
  int arow = m0 + am;
  const float* uA = u + (size_t)(base + (arow < cnt ? arow : 0)) * H_;
  bool avalid = arow < cnt;
  int bk = tid >> 4;
  int bn = (tid & 15) * 4;
  const float* W2e = W2 + (size_t)e * H_ * D_;
  for (int k0 = 0; k0 < H_; k0 += BK) {
#pragma unroll
    for (int q = 0; q < 4; ++q) {
      int k = akq + q;
      As[k][am] = avalid ? uA[k0 + k] : 0.f;
    }
    const float* bp = W2e + (size_t)(k0 + bk) * D_ + n0 + bn;
#pragma unroll
    for (int q = 0; q < 4; ++q) Bs[bk][bn + q] = bp[q];
    __syncthreads();
#pragma unroll
    for (int kk = 0; kk < BK; ++kk) {
      float a[4], b[4];
#pragma unroll
      for (int i = 0; i < 4; ++i) a[i] = As[kk][ty * 4 + i];
#pragma unroll
      for (int j = 0; j < 4; ++j) b[j] = Bs[kk][tx * 4 + j];
#pragma unroll
      for (int i = 0; i < 4; ++i)
#pragma unroll
        for (int j = 0; j < 4; ++j) acc[i][j] += a[i] * b[j];
    }
    __syncthreads();
  }
#pragma unroll
  for (int i = 0; i < 4; ++i) {
    int r = m0 + ty * 4 + i;
    if (r < cnt) {
      int tok = rowtok[base + r];
      float g = rowgate[base + r];
      float* hp = h + (size_t)tok * D_ + n0 + tx * 4;
#pragma unroll
      for (int j = 0; j < 4; ++j) atomicAdd(&hp[j], g * acc[i][j]);
    }
  }
}

// ---------------- final rmsnorm ----------------
__global__ void k_finalnorm(const float* __restrict__ h, const float* __restrict__ w,
                            float* __restrict__ fn) {
  int t = blockIdx.x;
  int tid = threadIdx.x;
  const float* hp = h + (size_t)t * D_;
  float ss = 0.f;
  for (int d = tid; d < D_; d += 256) {
    float x = hp[d];
    ss += x * x;
  }
  __shared__ float s[256];
  s[tid] = ss;
  __syncthreads();
  for (int o = 128; o > 0; o >>= 1) {
    if (tid < o) s[tid] += s[tid + o];
    __syncthreads();
  }
  float ir = rsqrtf(s[0] / (float)D_ + EPS_);
  for (int d = tid; d < D_; d += 256) fn[(size_t)t * D_ + d] = hp[d] * ir * w[d];
}

// ---------------- final GEMM: out[t,v] = fn[t,:] . embed[v,:] ----------------
__global__ void k_final_gemm(const float* __restrict__ fn, const float* __restrict__ embed,
                             float* __restrict__ out) {
  int m0 = blockIdx.x * BM;
  int n0 = blockIdx.y * BN;
  __shared__ float As[BK][BM];
  __shared__ float Bs[BK][BN];
  int tid = threadIdx.x;
  int tx = tid % 16, ty = tid / 16;
  float acc[4][4] = {};
  int am = tid >> 2;
  int akq = (tid & 3) * 4;
  int bn3 = tid >> 2;
  int bkq3 = (tid & 3) * 4;
  for (int k0 = 0; k0 < D_; k0 += BK) {
    const float* ap = fn + (size_t)(m0 + am) * D_ + k0 + akq;
#pragma unroll
    for (int q = 0; q < 4; ++q) As[akq + q][am] = ap[q];
    const float* bp = embed + (size_t)(n0 + bn3) * D_ + k0 + bkq3;
#pragma unroll
    for (int q = 0; q < 4; ++q) Bs[bkq3 + q][bn3] = bp[q];
    __syncthreads();
#pragma unroll
    for (int kk = 0; kk < BK; ++kk) {
      float a[4], b[4];
#pragma unroll
      for (int i = 0; i < 4; ++i) a[i] = As[kk][ty * 4 + i];
#pragma unroll
      for (int j = 0; j < 4; ++j) b[j] = Bs[kk][tx * 4 + j];
#pragma unroll
      for (int i = 0; i < 4; ++i)
#pragma unroll
        for (int j = 0; j < 4; ++j) acc[i][j] += a[i] * b[j];
    }
    __syncthreads();
  }
#pragma unroll
  for (int i = 0; i < 4; ++i) {
    float* op = out + (size_t)(m0 + ty * 4 + i) * V_ + n0 + tx * 4;
#pragma unroll
    for (int j = 0; j < 4; ++j) op[j] = acc[i][j];
  }
}

// ---------------- launch ----------------
extern "C" void kernel_launch(void* const* d_in, const int* in_sizes, int n_in,
                              void* d_out, int out_size, void* d_ws, size_t ws_size,
                              hipStream_t stream) {
  const int* ids = (const int*)d_in[0];
  const float* embed = (const float*)d_in[1];
  const float* router_ln = (const float*)d_in[2];
  const float* router_W = (const float*)d_in[3];
  const float* expert_ln = (const float*)d_in[4];
  const float* W1 = (const float*)d_in[5];
  const float* W2 = (const float*)d_in[6];
  const float* ln_out_w = (const float*)d_in[7];
  float* out = (float*)d_out;

  // workspace carve (bytes, 256-aligned)
  char* p = (char*)d_ws;
  auto carve = [&](size_t bytes) {
    char* r = p;
    p += (bytes + 255) & ~(size_t)255;
    return (void*)r;
  };
  float* h = (float*)carve((size_t)T_ * D_ * 4);
  float* fn = (float*)carve((size_t)T_ * D_ * 4);
  float* u = (float*)carve((size_t)T_ * K_ * H_ * 4);
  float* invr = (float*)carve((size_t)T_ * 4);
  int* eidx = (int*)carve((size_t)T_ * K_ * 4);
  float* gate = (float*)carve((size_t)T_ * K_ * 4);
  int* rowtok = (int*)carve((size_t)T_ * K_ * 4);
  float* rowgate = (float*)carve((size_t)T_ * K_ * 4);
  int* counts = (int*)carve(256);
  int* offsets = (int*)carve(256);
  int* cursor = (int*)carve(256);

  k_gather<<<T_, 256, 0, stream>>>(ids, embed, h);

  for (int hop = 0; hop < NHOPS_; ++hop) {
    const float* rln = router_ln + (size_t)hop * D_;
    const float* rW = router_W + (size_t)hop * D_ * E_;
    k_router<<<T_, 256, 0, stream>>>(h, rln, rW, invr, eidx, gate);
    k_zero_counts<<<1, 64, 0, stream>>>(counts, cursor);
    k_count<<<(T_ * K_) / 256, 256, 0, stream>>>(eidx, counts);
    k_scan<<<1, 64, 0, stream>>>(counts, offsets);
    k_fill<<<(T_ * K_) / 256, 256, 0, stream>>>(eidx, gate, offsets, cursor, rowtok, rowgate);
    k_expert_gemm1<<<dim3(T_ / BM, H_ / BN, E_), 256, 0, stream>>>(h, invr, expert_ln, W1, counts,
                                                                   offsets, rowtok, u);
    k_expert_gemm2<<<dim3(T_ / BM, D_ / BN, E_), 256, 0, stream>>>(u, W2, counts, offsets, rowtok,
                                                                   rowgate, h);
  }

  k_finalnorm<<<T_, 256, 0, stream>>>(h, ln_out_w, fn);
  k_final_gemm<<<dim3(T_ / BM, V_ / BN), 256, 0, stream>>>(fn, embed, out);
}

// Round 6
// 7121.316 us; speedup vs baseline: 2.1062x; 2.1062x over previous
//
#include <hip/hip_runtime.h>
#include <hip/hip_bf16.h>
#include <math.h>

// Problem constants (match reference)
#define V_ 32000
#define D_ 1024
#define E_ 8
#define H_ 4096
#define T_ 2048
#define NHOPS_ 4
#define K_ 2
#define EPS_ 1e-5f

// MFMA tiling: 64x64 block tile, BK=32, 4 waves (2x2), wave = 32x32 = 2x2 mfma 16x16x32
#define LDK 40  // padded LDS row stride in ushorts (80 B -> <=2-way bank conflicts)

typedef __attribute__((ext_vector_type(8))) short short8v;
typedef __attribute__((ext_vector_type(4))) float f32x4;

__device__ __forceinline__ unsigned short f2bf(float f) {
  union { float f; unsigned u; } v;
  v.f = f;
  unsigned r = v.u + 0x7FFF + ((v.u >> 16) & 1);  // RNE
  return (unsigned short)(r >> 16);
}
__device__ __forceinline__ float bf2f(unsigned short b) {
  union { unsigned u; float f; } v;
  v.u = ((unsigned)b) << 16;
  return v.f;
}
// split-bf16: v ~= hi + lo with ~2^-17 relative error (expert path must stay
// near-f32 so downstream top-2 routing decisions do not flip vs the reference)
__device__ __forceinline__ void split_bf(float v, unsigned short& hi, unsigned short& lo) {
  hi = f2bf(v);
  lo = f2bf(v - bf2f(hi));
}

__device__ __forceinline__ float gelu_f(float x) {
  float x3 = x * x * x;
  return 0.5f * x * (1.0f + tanhf(0.7978845608028654f * (x + 0.044715f * x3)));
}

// ---------------- gather: h[t,:] = embed_W[ids[t],:] ----------------
__global__ void k_gather(const int* __restrict__ ids, const float* __restrict__ embed,
                         float* __restrict__ h) {
  int t = blockIdx.x;
  const float4* src = (const float4*)(embed + (size_t)ids[t] * D_);
  float4* dst = (float4*)(h + (size_t)t * D_);
  dst[threadIdx.x] = src[threadIdx.x];
}

// ---------------- router: invr, top-2 expert ids + gates (verified, f32) ----------------
__global__ void k_router(const float* __restrict__ h, const float* __restrict__ rln,
                         const float* __restrict__ rW, float* __restrict__ invr,
                         int* __restrict__ eidx, float* __restrict__ gate) {
  int t = blockIdx.x;
  int tid = threadIdx.x;
  const float* hp = h + (size_t)t * D_;
  float lacc[E_] = {0.f, 0.f, 0.f, 0.f, 0.f, 0.f, 0.f, 0.f};
  float ss = 0.f;
  for (int d = tid; d < D_; d += 256) {
    float x = hp[d];
    ss += x * x;
    float xw = x * rln[d];
    const float* wr = rW + (size_t)d * E_;
#pragma unroll
    for (int e = 0; e < E_; ++e) lacc[e] += xw * wr[e];
  }
  __shared__ float s_l[256][E_];
  __shared__ float s_ss[256];
  __shared__ float s_lg[E_];
  __shared__ float s_ir;
#pragma unroll
  for (int e = 0; e < E_; ++e) s_l[tid][e] = lacc[e];
  s_ss[tid] = ss;
  __syncthreads();
  if (tid < E_) {
    float a = 0.f;
    for (int i = 0; i < 256; ++i) a += s_l[i][tid];
    s_lg[tid] = a;
  } else if (tid == E_) {
    float tot = 0.f;
    for (int i = 0; i < 256; ++i) tot += s_ss[i];
    s_ir = rsqrtf(tot / (float)D_ + EPS_);
  }
  __syncthreads();
  if (tid == 0) {
    float ir = s_ir;
    invr[t] = ir;
    float lg[E_];
#pragma unroll
    for (int e = 0; e < E_; ++e) lg[e] = s_lg[e] * ir;
    int i0 = 0;
#pragma unroll
    for (int e = 1; e < E_; ++e)
      if (lg[e] > lg[i0]) i0 = e;
    int i1 = (i0 == 0) ? 1 : 0;
#pragma unroll
    for (int e = 0; e < E_; ++e)
      if (e != i0 && lg[e] > lg[i1]) i1 = e;
    float m = lg[0];
#pragma unroll
    for (int e = 1; e < E_; ++e) m = fmaxf(m, lg[e]);
    float den = 0.f;
#pragma unroll
    for (int e = 0; e < E_; ++e) den += expf(lg[e] - m);
    eidx[t * 2 + 0] = i0;
    eidx[t * 2 + 1] = i1;
    gate[t * 2 + 0] = expf(lg[i0] - m) / den;
    gate[t * 2 + 1] = expf(lg[i1] - m) / den;
  }
}

// ---------------- grouping (verified) ----------------
__global__ void k_zero_counts(int* counts, int* cursor) {
  if (threadIdx.x < E_) {
    counts[threadIdx.x] = 0;
    cursor[threadIdx.x] = 0;
  }
}
__global__ void k_count(const int* __restrict__ eidx, int* __restrict__ counts) {
  int i = blockIdx.x * 256 + threadIdx.x;
  if (i < T_ * K_) atomicAdd(&counts[eidx[i]], 1);
}
__global__ void k_scan(const int* __restrict__ counts, int* __restrict__ offsets) {
  if (threadIdx.x == 0) {
    int a = 0;
    for (int e = 0; e < E_; ++e) {
      offsets[e] = a;
      a += counts[e];
    }
  }
}
__global__ void k_fill(const int* __restrict__ eidx, const float* __restrict__ gate,
                       const int* __restrict__ offsets, int* __restrict__ cursor,
                       int* __restrict__ rowtok, float* __restrict__ rowgate) {
  int i = blockIdx.x * 256 + threadIdx.x;
  if (i >= T_ * K_) return;
  int e = eidx[i];
  int p = atomicAdd(&cursor[e], 1);
  int r = offsets[e] + p;
  rowtok[r] = i >> 1;
  rowgate[r] = gate[i];
}

// ------- split-bf16 MFMA gemm1: u = gelu((h*invr*eln_e) @ W1_e), u stored hi+lo -------
__global__ void k_mfma_gemm1(const float* __restrict__ h, const float* __restrict__ invr,
                             const float* __restrict__ eln, const float* __restrict__ W1,
                             const int* __restrict__ counts, const int* __restrict__ offsets,
                             const int* __restrict__ rowtok, unsigned short* __restrict__ uHi,
                             unsigned short* __restrict__ uLo) {
  int e = blockIdx.z;
  int cnt = counts[e];
  int m0 = blockIdx.x * 64;
  if (m0 >= cnt) return;
  int n0 = blockIdx.y * 64;
  int base = offsets[e];

  __shared__ alignas(16) unsigned short Ah[64 * LDK];
  __shared__ alignas(16) unsigned short Al[64 * LDK];
  __shared__ alignas(16) unsigned short Bh[64 * LDK];
  __shared__ alignas(16) unsigned short Bl[64 * LDK];

  int tid = threadIdx.x;
  int lane = tid & 63;
  int wid = tid >> 6;
  int wr = wid >> 1, wc = wid & 1;
  int fr = lane & 15, fs = lane >> 4;

  int am = tid >> 2;
  int akq = (tid & 3) * 8;
  int arow = m0 + am;
  bool av = arow < cnt;
  int tok = 0;
  float sc = 0.f;
  if (av) {
    tok = rowtok[base + arow];
    sc = invr[tok];
  }
  const float* hA = h + (size_t)tok * D_;
  const float* elnE = eln + (size_t)e * D_;

  int bkg = tid & 3;
  int bn = tid >> 2;
  const float* W1e = W1 + (size_t)e * D_ * H_;

  f32x4 zero4 = {0.f, 0.f, 0.f, 0.f};
  f32x4 acc[2][2];
  acc[0][0] = zero4; acc[0][1] = zero4; acc[1][0] = zero4; acc[1][1] = zero4;

  for (int k0 = 0; k0 < D_; k0 += 32) {
    // ---- A stage: xn = h*invr*eln, split hi/lo
    {
      unsigned short ah8[8], al8[8];
      if (av) {
        const float* xp = hA + k0 + akq;
        const float* ep = elnE + k0 + akq;
#pragma unroll
        for (int q = 0; q < 8; ++q) split_bf(xp[q] * sc * ep[q], ah8[q], al8[q]);
      } else {
#pragma unroll
        for (int q = 0; q < 8; ++q) { ah8[q] = 0; al8[q] = 0; }
      }
      *(short8v*)&Ah[am * LDK + akq] = *(const short8v*)ah8;
      *(short8v*)&Al[am * LDK + akq] = *(const short8v*)al8;
    }
    // ---- B stage: W1[k][n] -> Bs[n][k], split hi/lo
    {
      unsigned short bh8[8], bl8[8];
      const float* wp = W1e + (size_t)(k0 + bkg * 8) * H_ + n0 + bn;
#pragma unroll
      for (int j = 0; j < 8; ++j) split_bf(wp[(size_t)j * H_], bh8[j], bl8[j]);
      *(short8v*)&Bh[bn * LDK + bkg * 8] = *(const short8v*)bh8;
      *(short8v*)&Bl[bn * LDK + bkg * 8] = *(const short8v*)bl8;
    }
    __syncthreads();
    short8v a0h = *(const short8v*)&Ah[(wr * 32 + fr) * LDK + fs * 8];
    short8v a1h = *(const short8v*)&Ah[(wr * 32 + 16 + fr) * LDK + fs * 8];
    short8v a0l = *(const short8v*)&Al[(wr * 32 + fr) * LDK + fs * 8];
    short8v a1l = *(const short8v*)&Al[(wr * 32 + 16 + fr) * LDK + fs * 8];
    short8v b0h = *(const short8v*)&Bh[(wc * 32 + fr) * LDK + fs * 8];
    short8v b1h = *(const short8v*)&Bh[(wc * 32 + 16 + fr) * LDK + fs * 8];
    short8v b0l = *(const short8v*)&Bl[(wc * 32 + fr) * LDK + fs * 8];
    short8v b1l = *(const short8v*)&Bl[(wc * 32 + 16 + fr) * LDK + fs * 8];
    // (hi+lo)x(hi+lo) ~= hihi + hilo + lohi  (drop lolo ~2^-34)
    acc[0][0] = __builtin_amdgcn_mfma_f32_16x16x32_bf16(a0h, b0h, acc[0][0], 0, 0, 0);
    acc[0][0] = __builtin_amdgcn_mfma_f32_16x16x32_bf16(a0h, b0l, acc[0][0], 0, 0, 0);
    acc[0][0] = __builtin_amdgcn_mfma_f32_16x16x32_bf16(a0l, b0h, acc[0][0], 0, 0, 0);
    acc[0][1] = __builtin_amdgcn_mfma_f32_16x16x32_bf16(a0h, b1h, acc[0][1], 0, 0, 0);
    acc[0][1] = __builtin_amdgcn_mfma_f32_16x16x32_bf16(a0h, b1l, acc[0][1], 0, 0, 0);
    acc[0][1] = __builtin_amdgcn_mfma_f32_16x16x32_bf16(a0l, b1h, acc[0][1], 0, 0, 0);
    acc[1][0] = __builtin_amdgcn_mfma_f32_16x16x32_bf16(a1h, b0h, acc[1][0], 0, 0, 0);
    acc[1][0] = __builtin_amdgcn_mfma_f32_16x16x32_bf16(a1h, b0l, acc[1][0], 0, 0, 0);
    acc[1][0] = __builtin_amdgcn_mfma_f32_16x16x32_bf16(a1l, b0h, acc[1][0], 0, 0, 0);
    acc[1][1] = __builtin_amdgcn_mfma_f32_16x16x32_bf16(a1h, b1h, acc[1][1], 0, 0, 0);
    acc[1][1] = __builtin_amdgcn_mfma_f32_16x16x32_bf16(a1h, b1l, acc[1][1], 0, 0, 0);
    acc[1][1] = __builtin_amdgcn_mfma_f32_16x16x32_bf16(a1l, b1h, acc[1][1], 0, 0, 0);
    __syncthreads();
  }
  // epilogue: gelu in f32, store u as split hi/lo
#pragma unroll
  for (int fi = 0; fi < 2; ++fi) {
#pragma unroll
    for (int i = 0; i < 4; ++i) {
      int row = m0 + wr * 32 + fi * 16 + fs * 4 + i;
      if (row < cnt) {
#pragma unroll
        for (int fj = 0; fj < 2; ++fj) {
          int col = n0 + wc * 32 + fj * 16 + fr;
          float g = gelu_f(acc[fi][fj][i]);
          unsigned short hi, lo;
          split_bf(g, hi, lo);
          size_t idx = (size_t)(base + row) * H_ + col;
          uHi[idx] = hi;
          uLo[idx] = lo;
        }
      }
    }
  }
}

// ------- split-bf16 MFMA gemm2: h[tok] += gate * (u @ W2_e) -------
__global__ void k_mfma_gemm2(const unsigned short* __restrict__ uHi,
                             const unsigned short* __restrict__ uLo,
                             const float* __restrict__ W2, const int* __restrict__ counts,
                             const int* __restrict__ offsets, const int* __restrict__ rowtok,
                             const float* __restrict__ rowgate, float* __restrict__ h) {
  int e = blockIdx.z;
  int cnt = counts[e];
  int m0 = blockIdx.x * 64;
  if (m0 >= cnt) return;
  int n0 = blockIdx.y * 64;
  int base = offsets[e];

  __shared__ alignas(16) unsigned short Ah[64 * LDK];
  __shared__ alignas(16) unsigned short Al[64 * LDK];
  __shared__ alignas(16) unsigned short Bh[64 * LDK];
  __shared__ alignas(16) unsigned short Bl[64 * LDK];

  int tid = threadIdx.x;
  int lane = tid & 63;
  int wid = tid >> 6;
  int wr = wid >> 1, wc = wid & 1;
  int fr = lane & 15, fs = lane >> 4;

  int am = tid >> 2;
  int akq = (tid & 3) * 8;
  int arow = m0 + am;
  bool av = arow < cnt;
  size_t arowoff = (size_t)(base + (av ? arow : 0)) * H_;

  int bkg = tid & 3;
  int bn = tid >> 2;
  const float* W2e = W2 + (size_t)e * H_ * D_;

  f32x4 zero4 = {0.f, 0.f, 0.f, 0.f};
  f32x4 acc[2][2];
  acc[0][0] = zero4; acc[0][1] = zero4; acc[1][0] = zero4; acc[1][1] = zero4;

  for (int k0 = 0; k0 < H_; k0 += 32) {
    if (av) {
      *(short8v*)&Ah[am * LDK + akq] = *(const short8v*)(uHi + arowoff + k0 + akq);
      *(short8v*)&Al[am * LDK + akq] = *(const short8v*)(uLo + arowoff + k0 + akq);
    } else {
      short8v z = {0, 0, 0, 0, 0, 0, 0, 0};
      *(short8v*)&Ah[am * LDK + akq] = z;
      *(short8v*)&Al[am * LDK + akq] = z;
    }
    {
      unsigned short bh8[8], bl8[8];
      const float* wp = W2e + (size_t)(k0 + bkg * 8) * D_ + n0 + bn;
#pragma unroll
      for (int j = 0; j < 8; ++j) split_bf(wp[(size_t)j * D_], bh8[j], bl8[j]);
      *(short8v*)&Bh[bn * LDK + bkg * 8] = *(const short8v*)bh8;
      *(short8v*)&Bl[bn * LDK + bkg * 8] = *(const short8v*)bl8;
    }
    __syncthreads();
    short8v a0h = *(const short8v*)&Ah[(wr * 32 + fr) * LDK + fs * 8];
    short8v a1h = *(const short8v*)&Ah[(wr * 32 + 16 + fr) * LDK + fs * 8];
    short8v a0l = *(const short8v*)&Al[(wr * 32 + fr) * LDK + fs * 8];
    short8v a1l = *(const short8v*)&Al[(wr * 32 + 16 + fr) * LDK + fs * 8];
    short8v b0h = *(const short8v*)&Bh[(wc * 32 + fr) * LDK + fs * 8];
    short8v b1h = *(const short8v*)&Bh[(wc * 32 + 16 + fr) * LDK + fs * 8];
    short8v b0l = *(const short8v*)&Bl[(wc * 32 + fr) * LDK + fs * 8];
    short8v b1l = *(const short8v*)&Bl[(wc * 32 + 16 + fr) * LDK + fs * 8];
    acc[0][0] = __builtin_amdgcn_mfma_f32_16x16x32_bf16(a0h, b0h, acc[0][0], 0, 0, 0);
    acc[0][0] = __builtin_amdgcn_mfma_f32_16x16x32_bf16(a0h, b0l, acc[0][0], 0, 0, 0);
    acc[0][0] = __builtin_amdgcn_mfma_f32_16x16x32_bf16(a0l, b0h, acc[0][0], 0, 0, 0);
    acc[0][1] = __builtin_amdgcn_mfma_f32_16x16x32_bf16(a0h, b1h, acc[0][1], 0, 0, 0);
    acc[0][1] = __builtin_amdgcn_mfma_f32_16x16x32_bf16(a0h, b1l, acc[0][1], 0, 0, 0);
    acc[0][1] = __builtin_amdgcn_mfma_f32_16x16x32_bf16(a0l, b1h, acc[0][1], 0, 0, 0);
    acc[1][0] = __builtin_amdgcn_mfma_f32_16x16x32_bf16(a1h, b0h, acc[1][0], 0, 0, 0);
    acc[1][0] = __builtin_amdgcn_mfma_f32_16x16x32_bf16(a1h, b0l, acc[1][0], 0, 0, 0);
    acc[1][0] = __builtin_amdgcn_mfma_f32_16x16x32_bf16(a1l, b0h, acc[1][0], 0, 0, 0);
    acc[1][1] = __builtin_amdgcn_mfma_f32_16x16x32_bf16(a1h, b1h, acc[1][1], 0, 0, 0);
    acc[1][1] = __builtin_amdgcn_mfma_f32_16x16x32_bf16(a1h, b1l, acc[1][1], 0, 0, 0);
    acc[1][1] = __builtin_amdgcn_mfma_f32_16x16x32_bf16(a1l, b1h, acc[1][1], 0, 0, 0);
    __syncthreads();
  }
#pragma unroll
  for (int fi = 0; fi < 2; ++fi) {
#pragma unroll
    for (int i = 0; i < 4; ++i) {
      int row = m0 + wr * 32 + fi * 16 + fs * 4 + i;
      if (row < cnt) {
        int tok = rowtok[base + row];
        float g = rowgate[base + row];
        float* hp = h + (size_t)tok * D_;
#pragma unroll
        for (int fj = 0; fj < 2; ++fj) {
          int col = n0 + wc * 32 + fj * 16 + fr;
          atomicAdd(&hp[col], g * acc[fi][fj][i]);
        }
      }
    }
  }
}

// ---------------- final rmsnorm -> bf16 ----------------
__global__ void k_finalnorm(const float* __restrict__ h, const float* __restrict__ w,
                            unsigned short* __restrict__ fnb) {
  int t = blockIdx.x;
  int tid = threadIdx.x;
  const float* hp = h + (size_t)t * D_;
  float ss = 0.f;
  for (int d = tid; d < D_; d += 256) {
    float x = hp[d];
    ss += x * x;
  }
  __shared__ float s[256];
  s[tid] = ss;
  __syncthreads();
  for (int o = 128; o > 0; o >>= 1) {
    if (tid < o) s[tid] += s[tid + o];
    __syncthreads();
  }
  float ir = rsqrtf(s[0] / (float)D_ + EPS_);
  for (int d = tid; d < D_; d += 256) fnb[(size_t)t * D_ + d] = f2bf(hp[d] * ir * w[d]);
}

// ---------------- MFMA final GEMM (single bf16): out[t,v] = fn[t,:] . embed[v,:] --------
__global__ void k_mfma_final(const unsigned short* __restrict__ fnb,
                             const float* __restrict__ embed, float* __restrict__ out) {
  int m0 = blockIdx.x * 64;
  int n0 = blockIdx.y * 64;

  __shared__ alignas(16) unsigned short As[64 * LDK];
  __shared__ alignas(16) unsigned short Bs[64 * LDK];

  int tid = threadIdx.x;
  int lane = tid & 63;
  int wid = tid >> 6;
  int wr = wid >> 1, wc = wid & 1;
  int fr = lane & 15, fs = lane >> 4;

  int am = tid >> 2;
  int akq = (tid & 3) * 8;
  const unsigned short* fA = fnb + (size_t)(m0 + am) * D_;

  int bn = tid >> 2;
  int bkq = (tid & 3) * 8;
  const float* eB = embed + (size_t)(n0 + bn) * D_;

  f32x4 zero4 = {0.f, 0.f, 0.f, 0.f};
  f32x4 acc[2][2];
  acc[0][0] = zero4; acc[0][1] = zero4; acc[1][0] = zero4; acc[1][1] = zero4;

  for (int k0 = 0; k0 < D_; k0 += 32) {
    *(short8v*)&As[am * LDK + akq] = *(const short8v*)(fA + k0 + akq);
    {
      float4 x0 = *(const float4*)(eB + k0 + bkq);
      float4 x1 = *(const float4*)(eB + k0 + bkq + 4);
      unsigned short b8[8];
      b8[0] = f2bf(x0.x); b8[1] = f2bf(x0.y); b8[2] = f2bf(x0.z); b8[3] = f2bf(x0.w);
      b8[4] = f2bf(x1.x); b8[5] = f2bf(x1.y); b8[6] = f2bf(x1.z); b8[7] = f2bf(x1.w);
      *(short8v*)&Bs[bn * LDK + bkq] = *(const short8v*)b8;
    }
    __syncthreads();
    short8v a0 = *(const short8v*)&As[(wr * 32 + fr) * LDK + fs * 8];
    short8v a1 = *(const short8v*)&As[(wr * 32 + 16 + fr) * LDK + fs * 8];
    short8v b0 = *(const short8v*)&Bs[(wc * 32 + fr) * LDK + fs * 8];
    short8v b1 = *(const short8v*)&Bs[(wc * 32 + 16 + fr) * LDK + fs * 8];
    acc[0][0] = __builtin_amdgcn_mfma_f32_16x16x32_bf16(a0, b0, acc[0][0], 0, 0, 0);
    acc[0][1] = __builtin_amdgcn_mfma_f32_16x16x32_bf16(a0, b1, acc[0][1], 0, 0, 0);
    acc[1][0] = __builtin_amdgcn_mfma_f32_16x16x32_bf16(a1, b0, acc[1][0], 0, 0, 0);
    acc[1][1] = __builtin_amdgcn_mfma_f32_16x16x32_bf16(a1, b1, acc[1][1], 0, 0, 0);
    __syncthreads();
  }
#pragma unroll
  for (int fi = 0; fi < 2; ++fi) {
#pragma unroll
    for (int i = 0; i < 4; ++i) {
      int row = m0 + wr * 32 + fi * 16 + fs * 4 + i;
      float* op = out + (size_t)row * V_;
#pragma unroll
      for (int fj = 0; fj < 2; ++fj) {
        int col = n0 + wc * 32 + fj * 16 + fr;
        op[col] = acc[fi][fj][i];
      }
    }
  }
}

// ---------------- launch ----------------
extern "C" void kernel_launch(void* const* d_in, const int* in_sizes, int n_in,
                              void* d_out, int out_size, void* d_ws, size_t ws_size,
                              hipStream_t stream) {
  const int* ids = (const int*)d_in[0];
  const float* embed = (const float*)d_in[1];
  const float* router_ln = (const float*)d_in[2];
  const float* router_W = (const float*)d_in[3];
  const float* expert_ln = (const float*)d_in[4];
  const float* W1 = (const float*)d_in[5];
  const float* W2 = (const float*)d_in[6];
  const float* ln_out_w = (const float*)d_in[7];
  float* out = (float*)d_out;

  char* p = (char*)d_ws;
  auto carve = [&](size_t bytes) {
    char* r = p;
    p += (bytes + 255) & ~(size_t)255;
    return (void*)r;
  };
  float* h = (float*)carve((size_t)T_ * D_ * 4);
  unsigned short* fnb = (unsigned short*)carve((size_t)T_ * D_ * 2);
  unsigned short* uHi = (unsigned short*)carve((size_t)T_ * K_ * H_ * 2);
  unsigned short* uLo = (unsigned short*)carve((size_t)T_ * K_ * H_ * 2);
  float* invr = (float*)carve((size_t)T_ * 4);
  int* eidx = (int*)carve((size_t)T_ * K_ * 4);
  float* gate = (float*)carve((size_t)T_ * K_ * 4);
  int* rowtok = (int*)carve((size_t)T_ * K_ * 4);
  float* rowgate = (float*)carve((size_t)T_ * K_ * 4);
  int* counts = (int*)carve(256);
  int* offsets = (int*)carve(256);
  int* cursor = (int*)carve(256);

  k_gather<<<T_, 256, 0, stream>>>(ids, embed, h);

  for (int hop = 0; hop < NHOPS_; ++hop) {
    const float* rln = router_ln + (size_t)hop * D_;
    const float* rW = router_W + (size_t)hop * D_ * E_;
    k_router<<<T_, 256, 0, stream>>>(h, rln, rW, invr, eidx, gate);
    k_zero_counts<<<1, 64, 0, stream>>>(counts, cursor);
    k_count<<<(T_ * K_) / 256, 256, 0, stream>>>(eidx, counts);
    k_scan<<<1, 64, 0, stream>>>(counts, offsets);
    k_fill<<<(T_ * K_) / 256, 256, 0, stream>>>(eidx, gate, offsets, cursor, rowtok, rowgate);
    k_mfma_gemm1<<<dim3(T_ / 64, H_ / 64, E_), 256, 0, stream>>>(h, invr, expert_ln, W1, counts,
                                                                 offsets, rowtok, uHi, uLo);
    k_mfma_gemm2<<<dim3(T_ / 64, D_ / 64, E_), 256, 0, stream>>>(uHi, uLo, W2, counts, offsets,
                                                                 rowtok, rowgate, h);
  }

  k_finalnorm<<<T_, 256, 0, stream>>>(h, ln_out_w, fnb);
  k_mfma_final<<<dim3(T_ / 64, V_ / 64), 256, 0, stream>>>(fnb, embed, out);
}

// Round 9
// 5725.670 us; speedup vs baseline: 2.6195x; 1.2438x over previous
//
#include <hip/hip_runtime.h>
#include <hip/hip_bf16.h>
#include <math.h>

// Problem constants (match reference)
#define V_ 32000
#define D_ 1024
#define E_ 8
#define H_ 4096
#define T_ 2048
#define NHOPS_ 4
#define K_ 2
#define EPS_ 1e-5f

// MFMA tiling: 64x64 block tile, BK=32, 4 waves (2x2), wave = 32x32 = 2x2 mfma 16x16x32
#define LDK 40  // padded LDS row stride in ushorts (80 B -> <=2-way bank conflicts)

typedef __attribute__((ext_vector_type(8))) short short8v;
typedef __attribute__((ext_vector_type(4))) float f32x4;

__device__ __forceinline__ unsigned short f2bf(float f) {
  union { float f; unsigned u; } v;
  v.f = f;
  unsigned r = v.u + 0x7FFF + ((v.u >> 16) & 1);  // RNE
  return (unsigned short)(r >> 16);
}
__device__ __forceinline__ float bf2f(unsigned short b) {
  union { unsigned u; float f; } v;
  v.u = ((unsigned)b) << 16;
  return v.f;
}
// split-bf16: v ~= hi + lo (~2^-17 rel). Expert path must stay near-f32 so
// downstream top-2 routing decisions do not flip vs the f32 reference.
__device__ __forceinline__ void split_bf(float v, unsigned short& hi, unsigned short& lo) {
  hi = f2bf(v);
  lo = f2bf(v - bf2f(hi));
}

__device__ __forceinline__ float gelu_f(float x) {
  float x3 = x * x * x;
  return 0.5f * x * (1.0f + tanhf(0.7978845608028654f * (x + 0.044715f * x3)));
}

// ------- once-per-launch: split W (f32 [E][R][C]) into transposed bf16 hi/lo [E][C][R] -------
__global__ void k_split_transpose(const float* __restrict__ src, unsigned short* __restrict__ dhi,
                                  unsigned short* __restrict__ dlo, int R, int C) {
  int e = blockIdx.z;
  int r0 = blockIdx.x * 64, c0 = blockIdx.y * 64;
  const float* s = src + (size_t)e * R * C;
  __shared__ float tile[64][65];
  int tid = threadIdx.x;
  int lr = tid >> 6;   // 0..3
  int lc = tid & 63;   // 0..63
#pragma unroll
  for (int p = 0; p < 16; ++p) {
    int rr = p * 4 + lr;
    tile[rr][lc] = s[(size_t)(r0 + rr) * C + c0 + lc];
  }
  __syncthreads();
  unsigned short* ph = dhi + (size_t)e * R * C;
  unsigned short* pl = dlo + (size_t)e * R * C;
#pragma unroll
  for (int p = 0; p < 16; ++p) {
    int cc = p * 4 + lr;
    float v = tile[lc][cc];  // 2-way bank alias only (free)
    unsigned short hi, lo;
    split_bf(v, hi, lo);
    size_t o = (size_t)(c0 + cc) * R + r0 + lc;
    ph[o] = hi;
    pl[o] = lo;
  }
}

// ---------------- gather: h[t,:] = embed_W[ids[t],:] ----------------
__global__ void k_gather(const int* __restrict__ ids, const float* __restrict__ embed,
                         float* __restrict__ h) {
  int t = blockIdx.x;
  const float4* src = (const float4*)(embed + (size_t)ids[t] * D_);
  float4* dst = (float4*)(h + (size_t)t * D_);
  dst[threadIdx.x] = src[threadIdx.x];
}

// ---------------- router: invr, top-2 expert ids + gates (verified, f32) ----------------
__global__ void k_router(const float* __restrict__ h, const float* __restrict__ rln,
                         const float* __restrict__ rW, float* __restrict__ invr,
                         int* __restrict__ eidx, float* __restrict__ gate) {
  int t = blockIdx.x;
  int tid = threadIdx.x;
  const float* hp = h + (size_t)t * D_;
  float lacc[E_] = {0.f, 0.f, 0.f, 0.f, 0.f, 0.f, 0.f, 0.f};
  float ss = 0.f;
  for (int d = tid; d < D_; d += 256) {
    float x = hp[d];
    ss += x * x;
    float xw = x * rln[d];
    const float* wr = rW + (size_t)d * E_;
#pragma unroll
    for (int e = 0; e < E_; ++e) lacc[e] += xw * wr[e];
  }
  __shared__ float s_l[256][E_];
  __shared__ float s_ss[256];
  __shared__ float s_lg[E_];
  __shared__ float s_ir;
#pragma unroll
  for (int e = 0; e < E_; ++e) s_l[tid][e] = lacc[e];
  s_ss[tid] = ss;
  __syncthreads();
  if (tid < E_) {
    float a = 0.f;
    for (int i = 0; i < 256; ++i) a += s_l[i][tid];
    s_lg[tid] = a;
  } else if (tid == E_) {
    float tot = 0.f;
    for (int i = 0; i < 256; ++i) tot += s_ss[i];
    s_ir = rsqrtf(tot / (float)D_ + EPS_);
  }
  __syncthreads();
  if (tid == 0) {
    float ir = s_ir;
    invr[t] = ir;
    float lg[E_];
#pragma unroll
    for (int e = 0; e < E_; ++e) lg[e] = s_lg[e] * ir;
    int i0 = 0;
#pragma unroll
    for (int e = 1; e < E_; ++e)
      if (lg[e] > lg[i0]) i0 = e;
    int i1 = (i0 == 0) ? 1 : 0;
#pragma unroll
    for (int e = 0; e < E_; ++e)
      if (e != i0 && lg[e] > lg[i1]) i1 = e;
    float m = lg[0];
#pragma unroll
    for (int e = 1; e < E_; ++e) m = fmaxf(m, lg[e]);
    float den = 0.f;
#pragma unroll
    for (int e = 0; e < E_; ++e) den += expf(lg[e] - m);
    eidx[t * 2 + 0] = i0;
    eidx[t * 2 + 1] = i1;
    gate[t * 2 + 0] = expf(lg[i0] - m) / den;
    gate[t * 2 + 1] = expf(lg[i1] - m) / den;
  }
}

// ---------------- grouping (verified) ----------------
__global__ void k_zero_counts(int* counts, int* cursor) {
  if (threadIdx.x < E_) {
    counts[threadIdx.x] = 0;
    cursor[threadIdx.x] = 0;
  }
}
__global__ void k_count(const int* __restrict__ eidx, int* __restrict__ counts) {
  int i = blockIdx.x * 256 + threadIdx.x;
  if (i < T_ * K_) atomicAdd(&counts[eidx[i]], 1);
}
__global__ void k_scan(const int* __restrict__ counts, int* __restrict__ offsets) {
  if (threadIdx.x == 0) {
    int a = 0;
    for (int e = 0; e < E_; ++e) {
      offsets[e] = a;
      a += counts[e];
    }
  }
}
__global__ void k_fill(const int* __restrict__ eidx, const float* __restrict__ gate,
                       const int* __restrict__ offsets, int* __restrict__ cursor,
                       int* __restrict__ rowtok, float* __restrict__ rowgate) {
  int i = blockIdx.x * 256 + threadIdx.x;
  if (i >= T_ * K_) return;
  int e = eidx[i];
  int p = atomicAdd(&cursor[e], 1);
  int r = offsets[e] + p;
  rowtok[r] = i >> 1;
  rowgate[r] = gate[i];
}

// ------- split-bf16 MFMA gemm1: u = gelu((h*invr*eln_e) @ W1_e), u stored hi+lo -------
// B operand comes pre-split + pre-transposed: W1T hi/lo [E][H][D] bf16
__global__ void k_mfma_gemm1(const float* __restrict__ h, const float* __restrict__ invr,
                             const float* __restrict__ eln,
                             const unsigned short* __restrict__ W1Thi,
                             const unsigned short* __restrict__ W1Tlo,
                             const int* __restrict__ counts, const int* __restrict__ offsets,
                             const int* __restrict__ rowtok, unsigned short* __restrict__ uHi,
                             unsigned short* __restrict__ uLo) {
  int e = blockIdx.z;
  int cnt = counts[e];
  int m0 = blockIdx.x * 64;
  if (m0 >= cnt) return;
  int n0 = blockIdx.y * 64;
  int base = offsets[e];

  __shared__ alignas(16) unsigned short Ah[64 * LDK];
  __shared__ alignas(16) unsigned short Al[64 * LDK];
  __shared__ alignas(16) unsigned short Bh[64 * LDK];
  __shared__ alignas(16) unsigned short Bl[64 * LDK];

  int tid = threadIdx.x;
  int lane = tid & 63;
  int wid = tid >> 6;
  int wr = wid >> 1, wc = wid & 1;
  int fr = lane & 15, fs = lane >> 4;

  int am = tid >> 2;
  int akq = (tid & 3) * 8;
  int arow = m0 + am;
  bool av = arow < cnt;
  int tok = 0;
  float sc = 0.f;
  if (av) {
    tok = rowtok[base + arow];
    sc = invr[tok];
  }
  const float* hA = h + (size_t)tok * D_;
  const float* elnE = eln + (size_t)e * D_;

  int bn = tid >> 2;
  int bkq = (tid & 3) * 8;
  const unsigned short* w1h = W1Thi + ((size_t)e * H_ + n0 + bn) * D_;
  const unsigned short* w1l = W1Tlo + ((size_t)e * H_ + n0 + bn) * D_;

  f32x4 zero4 = {0.f, 0.f, 0.f, 0.f};
  f32x4 acc[2][2];
  acc[0][0] = zero4; acc[0][1] = zero4; acc[1][0] = zero4; acc[1][1] = zero4;

  for (int k0 = 0; k0 < D_; k0 += 32) {
    // A stage: xn = h*invr*eln, split hi/lo in-register
    {
      unsigned short ah8[8], al8[8];
      if (av) {
        const float* xp = hA + k0 + akq;
        const float* ep = elnE + k0 + akq;
#pragma unroll
        for (int q = 0; q < 8; ++q) split_bf(xp[q] * sc * ep[q], ah8[q], al8[q]);
      } else {
#pragma unroll
        for (int q = 0; q < 8; ++q) { ah8[q] = 0; al8[q] = 0; }
      }
      *(short8v*)&Ah[am * LDK + akq] = *(const short8v*)ah8;
      *(short8v*)&Al[am * LDK + akq] = *(const short8v*)al8;
    }
    // B stage: pure vectorized bf16 copy (pre-split, contiguous in k)
    *(short8v*)&Bh[bn * LDK + bkq] = *(const short8v*)(w1h + k0 + bkq);
    *(short8v*)&Bl[bn * LDK + bkq] = *(const short8v*)(w1l + k0 + bkq);
    __syncthreads();
    short8v a0h = *(const short8v*)&Ah[(wr * 32 + fr) * LDK + fs * 8];
    short8v a1h = *(const short8v*)&Ah[(wr * 32 + 16 + fr) * LDK + fs * 8];
    short8v a0l = *(const short8v*)&Al[(wr * 32 + fr) * LDK + fs * 8];
    short8v a1l = *(const short8v*)&Al[(wr * 32 + 16 + fr) * LDK + fs * 8];
    short8v b0h = *(const short8v*)&Bh[(wc * 32 + fr) * LDK + fs * 8];
    short8v b1h = *(const short8v*)&Bh[(wc * 32 + 16 + fr) * LDK + fs * 8];
    short8v b0l = *(const short8v*)&Bl[(wc * 32 + fr) * LDK + fs * 8];
    short8v b1l = *(const short8v*)&Bl[(wc * 32 + 16 + fr) * LDK + fs * 8];
    // (hi+lo)x(hi+lo) ~= hihi + hilo + lohi (drop lolo ~2^-34)
    acc[0][0] = __builtin_amdgcn_mfma_f32_16x16x32_bf16(a0h, b0h, acc[0][0], 0, 0, 0);
    acc[0][0] = __builtin_amdgcn_mfma_f32_16x16x32_bf16(a0h, b0l, acc[0][0], 0, 0, 0);
    acc[0][0] = __builtin_amdgcn_mfma_f32_16x16x32_bf16(a0l, b0h, acc[0][0], 0, 0, 0);
    acc[0][1] = __builtin_amdgcn_mfma_f32_16x16x32_bf16(a0h, b1h, acc[0][1], 0, 0, 0);
    acc[0][1] = __builtin_amdgcn_mfma_f32_16x16x32_bf16(a0h, b1l, acc[0][1], 0, 0, 0);
    acc[0][1] = __builtin_amdgcn_mfma_f32_16x16x32_bf16(a0l, b1h, acc[0][1], 0, 0, 0);
    acc[1][0] = __builtin_amdgcn_mfma_f32_16x16x32_bf16(a1h, b0h, acc[1][0], 0, 0, 0);
    acc[1][0] = __builtin_amdgcn_mfma_f32_16x16x32_bf16(a1h, b0l, acc[1][0], 0, 0, 0);
    acc[1][0] = __builtin_amdgcn_mfma_f32_16x16x32_bf16(a1l, b0h, acc[1][0], 0, 0, 0);
    acc[1][1] = __builtin_amdgcn_mfma_f32_16x16x32_bf16(a1h, b1h, acc[1][1], 0, 0, 0);
    acc[1][1] = __builtin_amdgcn_mfma_f32_16x16x32_bf16(a1h, b1l, acc[1][1], 0, 0, 0);
    acc[1][1] = __builtin_amdgcn_mfma_f32_16x16x32_bf16(a1l, b1h, acc[1][1], 0, 0, 0);
    __syncthreads();
  }
#pragma unroll
  for (int fi = 0; fi < 2; ++fi) {
#pragma unroll
    for (int i = 0; i < 4; ++i) {
      int row = m0 + wr * 32 + fi * 16 + fs * 4 + i;
      if (row < cnt) {
#pragma unroll
        for (int fj = 0; fj < 2; ++fj) {
          int col = n0 + wc * 32 + fj * 16 + fr;
          float g = gelu_f(acc[fi][fj][i]);
          unsigned short hi, lo;
          split_bf(g, hi, lo);
          size_t idx = (size_t)(base + row) * H_ + col;
          uHi[idx] = hi;
          uLo[idx] = lo;
        }
      }
    }
  }
}

// ------- split-bf16 MFMA gemm2: h[tok] += gate * (u @ W2_e), W2T pre-split [E][D][H] -------
__global__ void k_mfma_gemm2(const unsigned short* __restrict__ uHi,
                             const unsigned short* __restrict__ uLo,
                             const unsigned short* __restrict__ W2Thi,
                             const unsigned short* __restrict__ W2Tlo,
                             const int* __restrict__ counts, const int* __restrict__ offsets,
                             const int* __restrict__ rowtok, const float* __restrict__ rowgate,
                             float* __restrict__ h) {
  int e = blockIdx.z;
  int cnt = counts[e];
  int m0 = blockIdx.x * 64;
  if (m0 >= cnt) return;
  int n0 = blockIdx.y * 64;
  int base = offsets[e];

  __shared__ alignas(16) unsigned short Ah[64 * LDK];
  __shared__ alignas(16) unsigned short Al[64 * LDK];
  __shared__ alignas(16) unsigned short Bh[64 * LDK];
  __shared__ alignas(16) unsigned short Bl[64 * LDK];

  int tid = threadIdx.x;
  int lane = tid & 63;
  int wid = tid >> 6;
  int wr = wid >> 1, wc = wid & 1;
  int fr = lane & 15, fs = lane >> 4;

  int am = tid >> 2;
  int akq = (tid & 3) * 8;
  int arow = m0 + am;
  bool av = arow < cnt;
  size_t arowoff = (size_t)(base + (av ? arow : 0)) * H_;

  int bn = tid >> 2;
  int bkq = (tid & 3) * 8;
  const unsigned short* w2h = W2Thi + ((size_t)e * D_ + n0 + bn) * H_;
  const unsigned short* w2l = W2Tlo + ((size_t)e * D_ + n0 + bn) * H_;

  f32x4 zero4 = {0.f, 0.f, 0.f, 0.f};
  f32x4 acc[2][2];
  acc[0][0] = zero4; acc[0][1] = zero4; acc[1][0] = zero4; acc[1][1] = zero4;

  for (int k0 = 0; k0 < H_; k0 += 32) {
    if (av) {
      *(short8v*)&Ah[am * LDK + akq] = *(const short8v*)(uHi + arowoff + k0 + akq);
      *(short8v*)&Al[am * LDK + akq] = *(const short8v*)(uLo + arowoff + k0 + akq);
    } else {
      short8v z = {0, 0, 0, 0, 0, 0, 0, 0};
      *(short8v*)&Ah[am * LDK + akq] = z;
      *(short8v*)&Al[am * LDK + akq] = z;
    }
    *(short8v*)&Bh[bn * LDK + bkq] = *(const short8v*)(w2h + k0 + bkq);
    *(short8v*)&Bl[bn * LDK + bkq] = *(const short8v*)(w2l + k0 + bkq);
    __syncthreads();
    short8v a0h = *(const short8v*)&Ah[(wr * 32 + fr) * LDK + fs * 8];
    short8v a1h = *(const short8v*)&Ah[(wr * 32 + 16 + fr) * LDK + fs * 8];
    short8v a0l = *(const short8v*)&Al[(wr * 32 + fr) * LDK + fs * 8];
    short8v a1l = *(const short8v*)&Al[(wr * 32 + 16 + fr) * LDK + fs * 8];
    short8v b0h = *(const short8v*)&Bh[(wc * 32 + fr) * LDK + fs * 8];
    short8v b1h = *(const short8v*)&Bh[(wc * 32 + 16 + fr) * LDK + fs * 8];
    short8v b0l = *(const short8v*)&Bl[(wc * 32 + fr) * LDK + fs * 8];
    short8v b1l = *(const short8v*)&Bl[(wc * 32 + 16 + fr) * LDK + fs * 8];
    acc[0][0] = __builtin_amdgcn_mfma_f32_16x16x32_bf16(a0h, b0h, acc[0][0], 0, 0, 0);
    acc[0][0] = __builtin_amdgcn_mfma_f32_16x16x32_bf16(a0h, b0l, acc[0][0], 0, 0, 0);
    acc[0][0] = __builtin_amdgcn_mfma_f32_16x16x32_bf16(a0l, b0h, acc[0][0], 0, 0, 0);
    acc[0][1] = __builtin_amdgcn_mfma_f32_16x16x32_bf16(a0h, b1h, acc[0][1], 0, 0, 0);
    acc[0][1] = __builtin_amdgcn_mfma_f32_16x16x32_bf16(a0h, b1l, acc[0][1], 0, 0, 0);
    acc[0][1] = __builtin_amdgcn_mfma_f32_16x16x32_bf16(a0l, b1h, acc[0][1], 0, 0, 0);
    acc[1][0] = __builtin_amdgcn_mfma_f32_16x16x32_bf16(a1h, b0h, acc[1][0], 0, 0, 0);
    acc[1][0] = __builtin_amdgcn_mfma_f32_16x16x32_bf16(a1h, b0l, acc[1][0], 0, 0, 0);
    acc[1][0] = __builtin_amdgcn_mfma_f32_16x16x32_bf16(a1l, b0h, acc[1][0], 0, 0, 0);
    acc[1][1] = __builtin_amdgcn_mfma_f32_16x16x32_bf16(a1h, b1h, acc[1][1], 0, 0, 0);
    acc[1][1] = __builtin_amdgcn_mfma_f32_16x16x32_bf16(a1h, b1l, acc[1][1], 0, 0, 0);
    acc[1][1] = __builtin_amdgcn_mfma_f32_16x16x32_bf16(a1l, b1h, acc[1][1], 0, 0, 0);
    __syncthreads();
  }
#pragma unroll
  for (int fi = 0; fi < 2; ++fi) {
#pragma unroll
    for (int i = 0; i < 4; ++i) {
      int row = m0 + wr * 32 + fi * 16 + fs * 4 + i;
      if (row < cnt) {
        int tok = rowtok[base + row];
        float g = rowgate[base + row];
        float* hp = h + (size_t)tok * D_;
#pragma unroll
        for (int fj = 0; fj < 2; ++fj) {
          int col = n0 + wc * 32 + fj * 16 + fr;
          atomicAdd(&hp[col], g * acc[fi][fj][i]);
        }
      }
    }
  }
}

// ---------------- final rmsnorm -> bf16 ----------------
__global__ void k_finalnorm(const float* __restrict__ h, const float* __restrict__ w,
                            unsigned short* __restrict__ fnb) {
  int t = blockIdx.x;
  int tid = threadIdx.x;
  const float* hp = h + (size_t)t * D_;
  float ss = 0.f;
  for (int d = tid; d < D_; d += 256) {
    float x = hp[d];
    ss += x * x;
  }
  __shared__ float s[256];
  s[tid] = ss;
  __syncthreads();
  for (int o = 128; o > 0; o >>= 1) {
    if (tid < o) s[tid] += s[tid + o];
    __syncthreads();
  }
  float ir = rsqrtf(s[0] / (float)D_ + EPS_);
  for (int d = tid; d < D_; d += 256) fnb[(size_t)t * D_ + d] = f2bf(hp[d] * ir * w[d]);
}

// ---------------- MFMA final GEMM (single bf16): out[t,v] = fn[t,:] . embed[v,:] --------
__global__ void k_mfma_final(const unsigned short* __restrict__ fnb,
                             const float* __restrict__ embed, float* __restrict__ out) {
  int m0 = blockIdx.x * 64;
  int n0 = blockIdx.y * 64;

  __shared__ alignas(16) unsigned short As[64 * LDK];
  __shared__ alignas(16) unsigned short Bs[64 * LDK];

  int tid = threadIdx.x;
  int lane = tid & 63;
  int wid = tid >> 6;
  int wr = wid >> 1, wc = wid & 1;
  int fr = lane & 15, fs = lane >> 4;

  int am = tid >> 2;
  int akq = (tid & 3) * 8;
  const unsigned short* fA = fnb + (size_t)(m0 + am) * D_;

  int bn = tid >> 2;
  int bkq = (tid & 3) * 8;
  const float* eB = embed + (size_t)(n0 + bn) * D_;

  f32x4 zero4 = {0.f, 0.f, 0.f, 0.f};
  f32x4 acc[2][2];
  acc[0][0] = zero4; acc[0][1] = zero4; acc[1][0] = zero4; acc[1][1] = zero4;

  for (int k0 = 0; k0 < D_; k0 += 32) {
    *(short8v*)&As[am * LDK + akq] = *(const short8v*)(fA + k0 + akq);
    {
      float4 x0 = *(const float4*)(eB + k0 + bkq);
      float4 x1 = *(const float4*)(eB + k0 + bkq + 4);
      unsigned short b8[8];
      b8[0] = f2bf(x0.x); b8[1] = f2bf(x0.y); b8[2] = f2bf(x0.z); b8[3] = f2bf(x0.w);
      b8[4] = f2bf(x1.x); b8[5] = f2bf(x1.y); b8[6] = f2bf(x1.z); b8[7] = f2bf(x1.w);
      *(short8v*)&Bs[bn * LDK + bkq] = *(const short8v*)b8;
    }
    __syncthreads();
    short8v a0 = *(const short8v*)&As[(wr * 32 + fr) * LDK + fs * 8];
    short8v a1 = *(const short8v*)&As[(wr * 32 + 16 + fr) * LDK + fs * 8];
    short8v b0 = *(const short8v*)&Bs[(wc * 32 + fr) * LDK + fs * 8];
    short8v b1 = *(const short8v*)&Bs[(wc * 32 + 16 + fr) * LDK + fs * 8];
    acc[0][0] = __builtin_amdgcn_mfma_f32_16x16x32_bf16(a0, b0, acc[0][0], 0, 0, 0);
    acc[0][1] = __builtin_amdgcn_mfma_f32_16x16x32_bf16(a0, b1, acc[0][1], 0, 0, 0);
    acc[1][0] = __builtin_amdgcn_mfma_f32_16x16x32_bf16(a1, b0, acc[1][0], 0, 0, 0);
    acc[1][1] = __builtin_amdgcn_mfma_f32_16x16x32_bf16(a1, b1, acc[1][1], 0, 0, 0);
    __syncthreads();
  }
#pragma unroll
  for (int fi = 0; fi < 2; ++fi) {
#pragma unroll
    for (int i = 0; i < 4; ++i) {
      int row = m0 + wr * 32 + fi * 16 + fs * 4 + i;
      float* op = out + (size_t)row * V_;
#pragma unroll
      for (int fj = 0; fj < 2; ++fj) {
        int col = n0 + wc * 32 + fj * 16 + fr;
        op[col] = acc[fi][fj][i];
      }
    }
  }
}

// ---------------- launch ----------------
extern "C" void kernel_launch(void* const* d_in, const int* in_sizes, int n_in,
                              void* d_out, int out_size, void* d_ws, size_t ws_size,
                              hipStream_t stream) {
  const int* ids = (const int*)d_in[0];
  const float* embed = (const float*)d_in[1];
  const float* router_ln = (const float*)d_in[2];
  const float* router_W = (const float*)d_in[3];
  const float* expert_ln = (const float*)d_in[4];
  const float* W1 = (const float*)d_in[5];
  const float* W2 = (const float*)d_in[6];
  const float* ln_out_w = (const float*)d_in[7];
  float* out = (float*)d_out;

  char* p = (char*)d_ws;
  auto carve = [&](size_t bytes) {
    char* r = p;
    p += (bytes + 255) & ~(size_t)255;
    return (void*)r;
  };
  float* h = (float*)carve((size_t)T_ * D_ * 4);
  unsigned short* fnb = (unsigned short*)carve((size_t)T_ * D_ * 2);
  unsigned short* uHi = (unsigned short*)carve((size_t)T_ * K_ * H_ * 2);
  unsigned short* uLo = (unsigned short*)carve((size_t)T_ * K_ * H_ * 2);
  unsigned short* w1thi = (unsigned short*)carve((size_t)E_ * D_ * H_ * 2);
  unsigned short* w1tlo = (unsigned short*)carve((size_t)E_ * D_ * H_ * 2);
  unsigned short* w2thi = (unsigned short*)carve((size_t)E_ * H_ * D_ * 2);
  unsigned short* w2tlo = (unsigned short*)carve((size_t)E_ * H_ * D_ * 2);
  float* invr = (float*)carve((size_t)T_ * 4);
  int* eidx = (int*)carve((size_t)T_ * K_ * 4);
  float* gate = (float*)carve((size_t)T_ * K_ * 4);
  int* rowtok = (int*)carve((size_t)T_ * K_ * 4);
  float* rowgate = (float*)carve((size_t)T_ * K_ * 4);
  int* counts = (int*)carve(256);
  int* offsets = (int*)carve(256);
  int* cursor = (int*)carve(256);

  // once per launch: split+transpose weights (constant across hops)
  k_split_transpose<<<dim3(D_ / 64, H_ / 64, E_), 256, 0, stream>>>(W1, w1thi, w1tlo, D_, H_);
  k_split_transpose<<<dim3(H_ / 64, D_ / 64, E_), 256, 0, stream>>>(W2, w2thi, w2tlo, H_, D_);

  k_gather<<<T_, 256, 0, stream>>>(ids, embed, h);

  for (int hop = 0; hop < NHOPS_; ++hop) {
    const float* rln = router_ln + (size_t)hop * D_;
    const float* rW = router_W + (size_t)hop * D_ * E_;
    k_router<<<T_, 256, 0, stream>>>(h, rln, rW, invr, eidx, gate);
    k_zero_counts<<<1, 64, 0, stream>>>(counts, cursor);
    k_count<<<(T_ * K_) / 256, 256, 0, stream>>>(eidx, counts);
    k_scan<<<1, 64, 0, stream>>>(counts, offsets);
    k_fill<<<(T_ * K_) / 256, 256, 0, stream>>>(eidx, gate, offsets, cursor, rowtok, rowgate);
    k_mfma_gemm1<<<dim3(T_ / 64, H_ / 64, E_), 256, 0, stream>>>(h, invr, expert_ln, w1thi, w1tlo,
                                                                 counts, offsets, rowtok, uHi, uLo);
    k_mfma_gemm2<<<dim3(T_ / 64, D_ / 64, E_), 256, 0, stream>>>(uHi, uLo, w2thi, w2tlo, counts,
                                                                 offsets, rowtok, rowgate, h);
  }

  k_finalnorm<<<T_, 256, 0, stream>>>(h, ln_out_w, fnb);
  k_mfma_final<<<dim3(T_ / 64, V_ / 64), 256, 0, stream>>>(fnb, embed, out);
}